// Round 3
// baseline (233.636 us; speedup 1.0000x reference)
//
#include <hip/hip_runtime.h>

#define N_NODES 16384
#define N_EDGES 262144
#define F_IN    128
#define DIM     64
#define N_CLS   40
#define KTERMS  24
#define EPSF    1e-8f

// ---------------- degree count (int) ----------------
__global__ __launch_bounds__(256) void k_degree(const int* __restrict__ dst,
                                                int* __restrict__ deg) {
    int e = blockIdx.x * 256 + threadIdx.x;
    if (e < N_EDGES) atomicAdd(&deg[dst[e]], 1);
}

// ---------------- exclusive prefix scan over 16384 ints, one block; also zeroes Mm ----------------
__global__ __launch_bounds__(1024) void k_scan(const int* __restrict__ deg,
                                               int* __restrict__ base,
                                               int* __restrict__ offs,
                                               float* __restrict__ Mm) {
    for (int i = threadIdx.x; i < KTERMS * (DIM + 1); i += 1024) Mm[i] = 0.f;

    const int tid = threadIdx.x, lane = tid & 63, w = tid >> 6;  // 16 waves
    int loc[16];
    int s = 0;
    const int b0 = tid * 16;
#pragma unroll
    for (int k = 0; k < 16; ++k) { loc[k] = s; s += deg[b0 + k]; }
    int v = s;
#pragma unroll
    for (int off = 1; off < 64; off <<= 1) {
        int t = __shfl_up(v, off);
        if (lane >= off) v += t;
    }
    __shared__ int wsum[16];
    if (lane == 63) wsum[w] = v;
    __syncthreads();
    if (w == 0 && lane < 16) {
        int x = wsum[lane];
#pragma unroll
        for (int off = 1; off < 16; off <<= 1) {
            int t = __shfl_up(x, off);
            if (lane >= off) x += t;
        }
        wsum[lane] = x;
    }
    __syncthreads();
    const int wbase = (w == 0) ? 0 : wsum[w - 1];
    const int excl  = wbase + v - s;
#pragma unroll
    for (int k = 0; k < 16; ++k) {
        int bb = excl + loc[k];
        base[b0 + k] = bb;
        offs[b0 + k] = bb;
    }
}

// ---------------- bucket edges by dst ----------------
__global__ __launch_bounds__(256) void k_bucket(const int* __restrict__ src,
                                                const int* __restrict__ dst,
                                                int* __restrict__ offs,
                                                int* __restrict__ ssrc) {
    int e = blockIdx.x * 256 + threadIdx.x;
    if (e < N_EDGES) {
        int pos = atomicAdd(&offs[dst[e]], 1);
        ssrc[pos] = src[e];
    }
}

// ---------------- fused layer 1: h1 = relu(mean_j x[src_j] @ W1l + x @ W1r + b1) ----------------
// Wave handles 4 nodes per group; gathers raw x (128-d, float2/lane), matvec from LDS weights.
__global__ __launch_bounds__(256) void k_sage1(const int* __restrict__ ssrc,
                                               const int* __restrict__ base,
                                               const int* __restrict__ deg,
                                               const float* __restrict__ x,
                                               const float* __restrict__ W1l,
                                               const float* __restrict__ W1r,
                                               const float* __restrict__ b1,
                                               float* __restrict__ h1) {
    __shared__ float sWl[F_IN * DIM];
    __shared__ float sWr[F_IN * DIM];
    __shared__ float sag[4][4][F_IN];
    __shared__ float sxr[4][4][F_IN];
    const int tid = threadIdx.x, lane = tid & 63, w = tid >> 6;

    const float4* wl4 = (const float4*)W1l;
    const float4* wr4 = (const float4*)W1r;
    float4* swl4 = (float4*)sWl;
    float4* swr4 = (float4*)sWr;
    for (int i = tid; i < F_IN * DIM / 4; i += 256) { swl4[i] = wl4[i]; swr4[i] = wr4[i]; }
    __syncthreads();

    const float bb = b1[lane];
    const int nw = gridDim.x * 4;
    for (int g = blockIdx.x * 4 + w; g < N_NODES / 4; g += nw) {
#pragma unroll
        for (int jj = 0; jj < 4; ++jj) {
            const int node = g * 4 + jj;
            const int s0 = base[node], d = deg[node];
            float2 acc = make_float2(0.f, 0.f);
            for (int j0 = 0; j0 < d; j0 += 64) {
                const int m = min(64, d - j0);
                const int eid = (lane < m) ? ssrc[s0 + j0 + lane] : 0;
                int t = 0;
                for (; t + 8 <= m; t += 8) {
                    float2 v[8];
#pragma unroll
                    for (int u = 0; u < 8; ++u) {
                        int s = __shfl(eid, t + u);
                        v[u] = ((const float2*)(x + (size_t)s * F_IN))[lane];
                    }
#pragma unroll
                    for (int u = 0; u < 8; ++u) { acc.x += v[u].x; acc.y += v[u].y; }
                }
                for (; t < m; ++t) {
                    int s = __shfl(eid, t);
                    float2 v = ((const float2*)(x + (size_t)s * F_IN))[lane];
                    acc.x += v.x; acc.y += v.y;
                }
            }
            const float inv = 1.f / fmaxf((float)d, 1.f);
            acc.x *= inv; acc.y *= inv;
            ((float2*)sag[w][jj])[lane] = acc;
            ((float2*)sxr[w][jj])[lane] = ((const float2*)(x + (size_t)node * F_IN))[lane];
        }
        float accl[4] = {0.f, 0.f, 0.f, 0.f};
        float accr[4] = {0.f, 0.f, 0.f, 0.f};
#pragma unroll 8
        for (int k = 0; k < F_IN; ++k) {
            const float wlv = sWl[k * DIM + lane];
            const float wrv = sWr[k * DIM + lane];
#pragma unroll
            for (int jj = 0; jj < 4; ++jj) {
                accl[jj] = fmaf(sag[w][jj][k], wlv, accl[jj]);
                accr[jj] = fmaf(sxr[w][jj][k], wrv, accr[jj]);
            }
        }
#pragma unroll
        for (int jj = 0; jj < 4; ++jj)
            h1[(size_t)(g * 4 + jj) * DIM + lane] = fmaxf(accl[jj] + accr[jj] + bb, 0.f);
    }
}

// ---------------- fused layer 2 + score + moments ----------------
__global__ __launch_bounds__(256) void k_sage2(const int* __restrict__ ssrc,
                                               const int* __restrict__ base,
                                               const int* __restrict__ deg,
                                               const float* __restrict__ h1,
                                               const float* __restrict__ W2l,
                                               const float* __restrict__ W2r,
                                               const float* __restrict__ b2,
                                               const float* __restrict__ aux,
                                               float* __restrict__ h2,
                                               float* __restrict__ score,
                                               float* __restrict__ Mm) {
    __shared__ float sWl[DIM * DIM];
    __shared__ float sWr[DIM * DIM];
    __shared__ float sag[4][4][DIM];
    __shared__ float shr[4][4][DIM];
    __shared__ float sM[KTERMS][DIM];
    __shared__ float smm[KTERMS];
    const int tid = threadIdx.x, lane = tid & 63, w = tid >> 6;

    const float4* wl4 = (const float4*)W2l;
    const float4* wr4 = (const float4*)W2r;
    float4* swl4 = (float4*)sWl;
    float4* swr4 = (float4*)sWr;
    for (int i = tid; i < DIM * DIM / 4; i += 256) { swl4[i] = wl4[i]; swr4[i] = wr4[i]; }
    __syncthreads();

    const float bb = b2[lane];
    const float av = aux[lane];
    float an2 = av * av;
#pragma unroll
    for (int off = 32; off >= 1; off >>= 1) an2 += __shfl_xor(an2, off);
    const float anorm = fmaxf(sqrtf(an2), EPSF);

    float accM[KTERMS], accm[KTERMS];
#pragma unroll
    for (int k = 0; k < KTERMS; ++k) { accM[k] = 0.f; accm[k] = 0.f; }

    const int nw = gridDim.x * 4;
    for (int g = blockIdx.x * 4 + w; g < N_NODES / 4; g += nw) {
#pragma unroll
        for (int jj = 0; jj < 4; ++jj) {
            const int node = g * 4 + jj;
            const int s0 = base[node], d = deg[node];
            float acc = 0.f;
            for (int j0 = 0; j0 < d; j0 += 64) {
                const int m = min(64, d - j0);
                const int eid = (lane < m) ? ssrc[s0 + j0 + lane] : 0;
                int t = 0;
                for (; t + 8 <= m; t += 8) {
                    float v[8];
#pragma unroll
                    for (int u = 0; u < 8; ++u) {
                        int s = __shfl(eid, t + u);
                        v[u] = h1[(size_t)s * DIM + lane];
                    }
#pragma unroll
                    for (int u = 0; u < 8; ++u) acc += v[u];
                }
                for (; t < m; ++t) {
                    int s = __shfl(eid, t);
                    acc += h1[(size_t)s * DIM + lane];
                }
            }
            sag[w][jj][lane] = acc / fmaxf((float)d, 1.f);
            shr[w][jj][lane] = h1[(size_t)node * DIM + lane];
        }
        float accl[4] = {0.f, 0.f, 0.f, 0.f};
        float accr[4] = {0.f, 0.f, 0.f, 0.f};
#pragma unroll 8
        for (int k = 0; k < DIM; ++k) {
            const float wlv = sWl[k * DIM + lane];
            const float wrv = sWr[k * DIM + lane];
#pragma unroll
            for (int jj = 0; jj < 4; ++jj) {
                accl[jj] = fmaf(sag[w][jj][k], wlv, accl[jj]);
                accr[jj] = fmaf(shr[w][jj][k], wrv, accr[jj]);
            }
        }
#pragma unroll
        for (int jj = 0; jj < 4; ++jj) {
            const int node = g * 4 + jj;
            const float hv = accl[jj] + accr[jj] + bb;
            h2[(size_t)node * DIM + lane] = hv;
            float d1 = hv * av, d2 = hv * hv;
#pragma unroll
            for (int off = 32; off >= 1; off >>= 1) {
                d1 += __shfl_xor(d1, off);
                d2 += __shfl_xor(d2, off);
            }
            const float s = d1 / (anorm * fmaxf(sqrtf(d2), EPSF));
            if (lane == 0) score[node] = s;
            float t = expf(-s * s);
#pragma unroll
            for (int k = 0; k < KTERMS; ++k) {
                accM[k] = fmaf(t, hv, accM[k]);
                accm[k] += t;
                t *= s;
            }
        }
    }

    __syncthreads();
    if (w == 0) {
#pragma unroll
        for (int k = 0; k < KTERMS; ++k) sM[k][lane] = accM[k];
        if (lane == 0)
            for (int k = 0; k < KTERMS; ++k) smm[k] = accm[k];
    }
    __syncthreads();
    if (w != 0) {
        for (int k = 0; k < KTERMS; ++k) atomicAdd(&sM[k][lane], accM[k]);
        if (lane == 0)
            for (int k = 0; k < KTERMS; ++k) atomicAdd(&smm[k], accm[k]);
    }
    __syncthreads();
    if (w == 0) {
        for (int k = 0; k < KTERMS; ++k) atomicAdd(&Mm[k * DIM + lane], sM[k][lane]);
        if (lane < KTERMS) atomicAdd(&Mm[KTERMS * DIM + lane], smm[lane]);
    }
}

// ---------------- fused z + classifier ----------------
__global__ __launch_bounds__(256) void k_zcls(const float* __restrict__ score,
                                              const float* __restrict__ Mm,
                                              const float* __restrict__ h,
                                              const float* __restrict__ Wc,
                                              const float* __restrict__ bc,
                                              float* __restrict__ out) {
    __shared__ float sM[KTERMS * DIM];
    __shared__ float sm[KTERMS];
    __shared__ float sW[2 * DIM * N_CLS];
    __shared__ float sb[N_CLS];
    __shared__ float sh[4][DIM];
    __shared__ float sz[4][DIM];
    const int tid = threadIdx.x;
    for (int idx = tid; idx < KTERMS * DIM; idx += 256) sM[idx] = Mm[idx];
    if (tid < KTERMS) sm[tid] = Mm[KTERMS * DIM + tid];
    for (int idx = tid; idx < 2 * DIM * N_CLS; idx += 256) sW[idx] = Wc[idx];
    if (tid < N_CLS) sb[tid] = bc[tid];
    __syncthreads();

    const int lane = tid & 63, w = tid >> 6;
    const int gw = blockIdx.x * 4 + w, nw = gridDim.x * 4;
    for (int i = gw; i < N_NODES; i += nw) {
        const float s2 = 2.f * score[i];
        float c = 1.f, num = 0.f, den = 0.f;
#pragma unroll
        for (int k = 0; k < KTERMS; ++k) {
            num = fmaf(c, sM[k * DIM + lane], num);
            den = fmaf(c, sm[k], den);
            c *= s2 * (1.0f / (float)(k + 1));
        }
        sz[w][lane] = num / den;
        sh[w][lane] = h[(size_t)i * DIM + lane];
        if (lane < N_CLS) {
            float acc = sb[lane];
#pragma unroll 8
            for (int k = 0; k < DIM; ++k)
                acc = fmaf(sh[w][k], sW[k * N_CLS + lane], acc);
#pragma unroll 8
            for (int k = 0; k < DIM; ++k)
                acc = fmaf(sz[w][k], sW[(DIM + k) * N_CLS + lane], acc);
            out[(size_t)i * N_CLS + lane] = acc;
        }
    }
}

extern "C" void kernel_launch(void* const* d_in, const int* in_sizes, int n_in,
                              void* d_out, int out_size, void* d_ws, size_t ws_size,
                              hipStream_t stream) {
    const float* x   = (const float*)d_in[0];
    const int*   ei  = (const int*)d_in[1];
    const float* W1l = (const float*)d_in[2];
    const float* b1  = (const float*)d_in[3];
    const float* W1r = (const float*)d_in[4];
    const float* W2l = (const float*)d_in[5];
    const float* b2  = (const float*)d_in[6];
    const float* W2r = (const float*)d_in[7];
    const float* aux = (const float*)d_in[8];
    const float* Wc  = (const float*)d_in[9];
    const float* bc  = (const float*)d_in[10];
    float*       out = (float*)d_out;

    const int* src = ei;
    const int* dst = ei + N_EDGES;

    float*       W  = (float*)d_ws;
    const size_t ND = (size_t)N_NODES * DIM;
    float* h1    = W;
    float* hh    = W + ND;
    float* score = W + 2 * ND;
    int*   deg   = (int*)(score + N_NODES);
    float* Mm    = (float*)(deg + N_NODES);
    int*   base  = (int*)(Mm + KTERMS * (DIM + 1));
    int*   offs  = base + N_NODES;
    int*   ssrc  = offs + N_NODES;

    hipMemsetAsync(deg, 0, N_NODES * sizeof(int), stream);
    k_degree<<<N_EDGES / 256, 256, 0, stream>>>(dst, deg);
    k_scan<<<1, 1024, 0, stream>>>(deg, base, offs, Mm);
    k_bucket<<<N_EDGES / 256, 256, 0, stream>>>(src, dst, offs, ssrc);

    k_sage1<<<512, 256, 0, stream>>>(ssrc, base, deg, x, W1l, W1r, b1, h1);
    k_sage2<<<512, 256, 0, stream>>>(ssrc, base, deg, h1, W2l, W2r, b2, aux, hh, score, Mm);
    k_zcls<<<512, 256, 0, stream>>>(score, Mm, hh, Wc, bc, out);
}